// Round 3
// baseline (2060.170 us; speedup 1.0000x reference)
//
#include <hip/hip_runtime.h>

typedef unsigned short ushort_t;
typedef __attribute__((ext_vector_type(8))) short bf16x8;
typedef __attribute__((ext_vector_type(4))) float f32x4;

#define DEV __device__ __forceinline__

DEV ushort_t f2bf(float x) {
  union { float f; unsigned u; } v; v.f = x;
  unsigned r = v.u + 0x7fffu + ((v.u >> 16) & 1u);
  return (ushort_t)(r >> 16);
}
DEV float bf2f(ushort_t b) {
  union { unsigned u; float f; } v; v.u = ((unsigned)b) << 16; return v.f;
}
DEV float sigf(float x) { return 1.f / (1.f + __expf(-x)); }

// ---------------- ws layout (bytes), total 0x8600000 = 134 MiB ----------------
#define OFF_WIT   0x0u        // WiT_perm  [2048][256] bf16   (1 MiB)
#define OFF_WHT   0x100000u   // WhT_perm  [2048][512] bf16   (2 MiB)
#define OFF_QKVT  0x300000u   // QKVT      [1024][512] bf16   (1 MiB)
#define OFF_WOT   0x400000u   // WoT       [512][512]  bf16   (0.5 MiB)
#define OFF_WDT   0x480000u   // WdT       [256][512]  bf16   (0.25 MiB)
#define OFF_BP    0x4C0000u   // bP        [2048] f32
#define OFF_HB0   0x500000u   // h ping    [128][512] bf16
#define OFF_HB1   0x520000u   // h pong
#define OFF_CST   0x540000u   // c state   [128][512] f32 (ends 0x580000)
#define OFF_SERT  0x600000u   // seriesT [128][256][256] bf16, 16 MiB (dead after last chunk gemm)
#define OFF_XZC   0x1600000u  // xz chunk [128n][64t][2048] bf16, 32 MiB (alive during LSTM)
#define OFF_HID   0x3600000u  // hid bf16 [32768][512] rows=(b,d,t), 32 MiB (alive to end)
#define OFF_NORM  0x600000u   // normed bf16 [32768][512] rows=(b,t,d)  (over sert; LN->QKV)
#define OFF_KB    0x2600000u  // k bf16 [32768][256] 16 MiB (over xzc lo; QKV->attn)
#define OFF_QB    0x5600000u  // q bf16 [32768][512] 32 MiB (QKV->attn)
#define OFF_VB    0x7600000u  // v bf16 [32768][256] 16 MiB (QKV->attn)
#define OFF_O     0x600000u   // attn out bf16 [32768][512] (over normed; attn->Wo gemm)
#define OFF_MIX   0x5600000u  // mix bf16 [32768][512] (over q; Wo gemm->final)

// ---------------- prep: weight permute/transpose/bf16 + state zero ----------------
// WiT_perm[j'][i] = Wi[i][512g+u], j' = 4u+g  (gate quads adjacent)
__global__ __launch_bounds__(256) void prep_kernel(
    const float* Wi, const float* Wh, const float* Wq, const float* Wk,
    const float* Wv, const float* Wo, const float* Wd, const float* b,
    char* ws) {
  unsigned i = blockIdx.x * 256 + threadIdx.x;
  if (i < 524288u) {                       // WiT
    unsigned j = i >> 8, ii = i & 255u;
    ((ushort_t*)(ws + OFF_WIT))[i] = f2bf(Wi[ii * 2048u + 512u * (j & 3u) + (j >> 2)]);
  } else if (i < 1572864u) {               // WhT
    unsigned x = i - 524288u; unsigned j = x >> 9, k = x & 511u;
    ((ushort_t*)(ws + OFF_WHT))[x] = f2bf(Wh[(size_t)k * 2048u + 512u * (j & 3u) + (j >> 2)]);
  } else if (i < 2097152u) {               // QKVT = [WqT|WkT|WvT]
    unsigned x = i - 1572864u; unsigned j = x >> 9, k = x & 511u;
    float v = (j < 512u) ? Wq[k * 512u + j] : (j < 768u) ? Wk[k * 256u + (j - 512u)]
                                                          : Wv[k * 256u + (j - 768u)];
    ((ushort_t*)(ws + OFF_QKVT))[x] = f2bf(v);
  } else if (i < 2359296u) {               // WoT
    unsigned x = i - 2097152u; unsigned j = x >> 9, k = x & 511u;
    ((ushort_t*)(ws + OFF_WOT))[x] = f2bf(Wo[k * 512u + j]);
  } else if (i < 2490368u) {               // WdT
    unsigned x = i - 2359296u; unsigned j = x >> 9, k = x & 511u;
    ((ushort_t*)(ws + OFF_WDT))[x] = f2bf(Wd[k * 256u + j]);
  } else if (i < 2492416u) {               // bP
    unsigned x = i - 2490368u;
    ((float*)(ws + OFF_BP))[x] = b[512u * (x & 3u) + (x >> 2)];
  } else if (i < 2623488u) {               // hb0+hb1 zero
    unsigned x = i - 2492416u;
    ((ushort_t*)(ws + OFF_HB0))[x] = 0;
  } else if (i < 2754560u) {               // c zero
    unsigned x = i - 2623488u;
    ((float*)(ws + OFF_CST))[x] = 0.f;
  }
}

// ---------------- seriesT: [n][s][i] = bf16(series[n][i][s]) ----------------
__global__ __launch_bounds__(256) void transpose_kernel(const float* series, ushort_t* sert) {
  __shared__ __align__(16) float tl[64][65];
  int n = blockIdx.x;
  int i0 = (blockIdx.y & 3) * 64, s0 = (blockIdx.y >> 2) * 64;
  int tc = threadIdx.x & 63, tr = threadIdx.x >> 6;
  const float* src = series + (size_t)n * 65536u;
#pragma unroll
  for (int p = 0; p < 16; ++p) {
    int r = p * 4 + tr;
    tl[r][tc] = src[(size_t)(i0 + r) * 256u + s0 + tc];
  }
  __syncthreads();
  ushort_t* dst = sert + (size_t)n * 65536u;
#pragma unroll
  for (int p = 0; p < 16; ++p) {
    int sr = p * 4 + tr;
    dst[(size_t)(s0 + sr) * 256u + i0 + tc] = f2bf(tl[tc][sr]);
  }
}

// ------------- generic bf16 MFMA GEMM, 64x64 tile, BK=256 K-passes, 64KiB LDS -------------
// A [M][K] bf16 row-major, BT [N][K] bf16 row-major.
// MODE 1: bf16 out split q/k/v (NTOT=1024)
// MODE 2: bf16 out (mix, NTOT=512)
// MODE 3: A = bf16(hid[m] + mix[n2(m)]) (both bf16), f32 out (NTOT=256)
// MODE 4: xz chunk: A row remap (m -> sert row n*256 + t0 + (m&63)), +bias, bf16 out
template <int K, int NTOT, int MODE>
__global__ __launch_bounds__(256) void gemm_kernel(
    const ushort_t* A, const ushort_t* BT, const float* bias,
    ushort_t* outb, ushort_t* ob1, ushort_t* ob2, float* outf,
    const ushort_t* Ahid, const ushort_t* Amix, int t0) {
  __shared__ __align__(16) unsigned char smem[128 * 512];  // A 64x256 | B 64x256 bf16 swizzled
  const int tid = threadIdx.x;
  const int m0 = blockIdx.x * 64;
  const int j0 = blockIdx.y * 64;
  const int w = tid >> 6, l = tid & 63;
  const int lo16 = l & 15, hi4 = l >> 4;
  f32x4 acc[4];
#pragma unroll
  for (int s = 0; s < 4; ++s) acc[s] = (f32x4)(0.f);

  for (int kt = 0; kt < K / 256; ++kt) {
    // stage 128 rows x 32 16B-chunks
#pragma unroll
    for (int it = 0; it < 16; ++it) {
      int ci = it * 256 + tid;
      int r = ci >> 5, cb = ci & 31;
      bf16x8 val;
      if (MODE == 3 && r < 64) {
        int m = m0 + r;
        int bb = m >> 11, dd = (m >> 8) & 7, tt = m & 255;
        int n2 = ((bb << 8) + tt) * 8 + dd;
        const ushort_t* hp = Ahid + (size_t)m * 512u + kt * 256 + cb * 8;
        const ushort_t* mp = Amix + (size_t)n2 * 512u + kt * 256 + cb * 8;
#pragma unroll
        for (int j = 0; j < 8; ++j) val[j] = (short)f2bf(bf2f(hp[j]) + bf2f(mp[j]));
      } else if (r < 64) {
        int m = m0 + r;
        size_t row = (MODE == 4) ? ((size_t)(m >> 6) * 256u + (unsigned)t0 + (m & 63))
                                 : (size_t)m;
        val = *(const bf16x8*)(A + row * K + kt * 256 + cb * 8);
      } else {
        val = *(const bf16x8*)(BT + (size_t)(j0 + (r - 64)) * K + kt * 256 + cb * 8);
      }
      int rr = r & 63;
      unsigned char* base = smem + ((r < 64) ? 0 : 64 * 512);
      *(bf16x8*)(base + rr * 512 + ((cb * 16) ^ ((rr & 7) << 4))) = val;
    }
    __syncthreads();

    const unsigned char* As = smem;
    const unsigned char* Bs = smem + 64 * 512;
    const int rB = 16 * w + lo16;
    const unsigned char* bbase = Bs + rB * 512;
    const int bswz = (rB & 7) << 4;
    const int aswz = (lo16 & 7) << 4;
#pragma unroll
    for (int kk = 0; kk < 256; kk += 32) {
      const int kb = kk * 2 + hi4 * 16;
      bf16x8 bf = *(const bf16x8*)(bbase + (kb ^ bswz));
#pragma unroll
      for (int s = 0; s < 4; ++s) {
        const int rA = 16 * s + lo16;
        bf16x8 af = *(const bf16x8*)(As + rA * 512 + (kb ^ aswz));
        acc[s] = __builtin_amdgcn_mfma_f32_16x16x32_bf16(af, bf, acc[s], 0, 0, 0);
      }
    }
    __syncthreads();
  }

  // -------- epilogue --------
  const int col = j0 + 16 * w + lo16;
#pragma unroll
  for (int s = 0; s < 4; ++s) {
#pragma unroll
    for (int jj = 0; jj < 4; ++jj) {
      int m = m0 + 16 * s + hi4 * 4 + jj;
      float v = acc[s][jj];
      if (MODE == 4) {
        outb[(size_t)m * NTOT + col] = f2bf(v + bias[col]);
      } else if (MODE == 1) {
        if (col < 512) outb[(size_t)m * 512u + col] = f2bf(v);
        else if (col < 768) ob1[(size_t)m * 256u + (col - 512)] = f2bf(v);
        else ob2[(size_t)m * 256u + (col - 768)] = f2bf(v);
      } else if (MODE == 2) {
        outb[(size_t)m * NTOT + col] = f2bf(v);
      } else {
        outf[(size_t)m * NTOT + col] = v;
      }
    }
  }
}

// ------- LSTM step: z = xzc[:,t&63,:] + h@WhT_perm ; gates ; c,h update. 57KiB LDS -------
// grid (2, 64): m-tile 64 batch rows, n-tile 32 cols (8 units * 4 gates)
__global__ __launch_bounds__(256) void lstm_step_kernel(
    const ushort_t* hprev, ushort_t* hnext, float* cstate, const ushort_t* WhT,
    const ushort_t* xzc, ushort_t* hidb, int t) {
  __shared__ __align__(16) unsigned char smem[96 * 512 + 64 * 36 * 4];
  const int tid = threadIdx.x;
  const int m0 = blockIdx.x * 64;
  const int j0 = blockIdx.y * 32;
  const int w = tid >> 6, l = tid & 63;
  const int lo16 = l & 15, hi4 = l >> 4;
  const int wr = w >> 1, wc = w & 1;
  f32x4 acc[2];
  acc[0] = (f32x4)(0.f); acc[1] = (f32x4)(0.f);

  for (int kt = 0; kt < 2; ++kt) {
    // stage A=hprev 64 rows (r<64), B=WhT 32 rows (r>=64); 96x32 chunks
#pragma unroll
    for (int it = 0; it < 12; ++it) {
      int ci = it * 256 + tid;
      int r = ci >> 5, cb = ci & 31;
      const ushort_t* src = (r < 64)
          ? hprev + (size_t)(m0 + r) * 512u + kt * 256 + cb * 8
          : WhT + (size_t)(j0 + (r - 64)) * 512u + kt * 256 + cb * 8;
      bf16x8 val = *(const bf16x8*)src;
      int rr = (r < 64) ? r : (r - 64);
      unsigned char* base = smem + ((r < 64) ? 0 : 64 * 512);
      *(bf16x8*)(base + rr * 512 + ((cb * 16) ^ ((rr & 7) << 4))) = val;
    }
    __syncthreads();

    const unsigned char* As = smem;
    const unsigned char* Bs = smem + 64 * 512;
    const int rB = 16 * wc + lo16;
    const unsigned char* bbase = Bs + rB * 512;
    const int bswz = (rB & 7) << 4;
    const int aswz = (lo16 & 7) << 4;
#pragma unroll
    for (int kk = 0; kk < 256; kk += 32) {
      const int kb = kk * 2 + hi4 * 16;
      bf16x8 bf = *(const bf16x8*)(bbase + (kb ^ bswz));
#pragma unroll
      for (int s = 0; s < 2; ++s) {
        const int rA = 32 * wr + 16 * s + lo16;
        bf16x8 af = *(const bf16x8*)(As + rA * 512 + (kb ^ aswz));
        acc[s] = __builtin_amdgcn_mfma_f32_16x16x32_bf16(af, bf, acc[s], 0, 0, 0);
      }
    }
    __syncthreads();
  }

  // z tile (+xz) -> LDS [64][36] f32
  float* zl = (float*)(smem + 96 * 512);
  const int colz = 16 * wc + lo16;
#pragma unroll
  for (int s = 0; s < 2; ++s) {
#pragma unroll
    for (int jj = 0; jj < 4; ++jj) {
      int row = 32 * wr + 16 * s + hi4 * 4 + jj;
      float xzv = bf2f(xzc[((size_t)(m0 + row) * 64u + (t & 63)) * 2048u + j0 + colz]);
      zl[row * 36 + colz] = acc[s][jj] + xzv;
    }
  }
  __syncthreads();

  // gate update: thread -> (row = tid>>2, 2 units)
  const int row = tid >> 2, ub = tid & 3;
  const int n = m0 + row;
#pragma unroll
  for (int uu = 0; uu < 2; ++uu) {
    int ul = ub * 2 + uu;
    float4 z4 = *(float4*)&zl[row * 36 + ul * 4];
    float ig = sigf(z4.x);
    float fg = sigf(z4.y);
    float gg = tanhf(z4.z);
    float og = sigf(z4.w);
    int U = (j0 >> 2) + ul;
    size_t ci = (size_t)n * 512u + U;
    float c = cstate[ci];
    c = fg * c + ig * gg;
    cstate[ci] = c;
    float h = og * tanhf(c);
    ushort_t hb = f2bf(h);
    hnext[ci] = hb;
    hidb[((size_t)n * 256u + t) * 512u + U] = hb;
  }
}

// -------- LayerNorm: hid bf16 row m=(b,d,t) -> normed bf16 row n2=(b,t,d) --------
__global__ __launch_bounds__(256) void ln_kernel(const ushort_t* hidb, const float* sc,
                                                 const float* bi, ushort_t* normed) {
  int row = blockIdx.x * 4 + (threadIdx.x >> 6);
  int l = threadIdx.x & 63;
  bf16x8 hv = *(const bf16x8*)(hidb + (size_t)row * 512u + l * 8);
  float v[8];
  float s1 = 0.f, s2 = 0.f;
#pragma unroll
  for (int j = 0; j < 8; ++j) {
    v[j] = bf2f((ushort_t)hv[j]);
    s1 += v[j]; s2 += v[j] * v[j];
  }
#pragma unroll
  for (int off = 1; off < 64; off <<= 1) {
    s1 += __shfl_xor(s1, off);
    s2 += __shfl_xor(s2, off);
  }
  float mu = s1 * (1.f / 512.f);
  float var = s2 * (1.f / 512.f) - mu * mu;
  float rs = rsqrtf(var + 1e-6f);
  int bb = row >> 11, dd = (row >> 8) & 7, tt = row & 255;
  int n2 = ((bb << 8) + tt) * 8 + dd;
  bf16x8 o;
#pragma unroll
  for (int j = 0; j < 8; ++j)
    o[j] = (short)f2bf((v[j] - mu) * rs * sc[l * 8 + j] + bi[l * 8 + j]);
  *(bf16x8*)(normed + (size_t)n2 * 512u + l * 8) = o;
}

// -------- attention: per (bt, head) 8x8 GQA + qk_norm, bf16 in/out --------
__global__ __launch_bounds__(256) void attn_kernel(const ushort_t* qb, const ushort_t* kb,
                                                   const ushort_t* vb, const float* qn,
                                                   const float* kn, ushort_t* ob) {
  __shared__ __align__(16) float sm[4][3240];  // per wave: q[8][132], k[8][132], v[8][132], a[8][9]
  const int n = blockIdx.x;
  const int w = threadIdx.x >> 6;
  const int l = threadIdx.x & 63;
  const int dq = l >> 3, c = l & 7;
  float* q_s = &sm[w][0];
  float* k_s = q_s + 1056;
  float* v_s = k_s + 1056;
  float* a_s = v_s + 1056;
  const int hk = w >> 1;

  // q row dq, chunk c (16 vals) + qk_norm (1/sqrt(128) folded)
  {
    const ushort_t* src = qb + ((size_t)n * 8u + dq) * 512u + w * 128 + c * 16;
    bf16x8 a0 = *(const bf16x8*)src, a1 = *(const bf16x8*)(src + 8);
    float v[16], s1 = 0.f, s2 = 0.f;
#pragma unroll
    for (int j = 0; j < 16; ++j) {
      v[j] = bf2f((ushort_t)(j < 8 ? a0[j] : a1[j - 8]));
      s1 += v[j]; s2 += v[j] * v[j];
    }
    for (int off = 1; off < 8; off <<= 1) { s1 += __shfl_xor(s1, off); s2 += __shfl_xor(s2, off); }
    float mu = s1 * (1.f / 128.f);
    float rs = rsqrtf(s2 * (1.f / 128.f) - mu * mu + 1e-6f);
#pragma unroll
    for (int j = 0; j < 16; ++j)
      q_s[dq * 132 + c * 16 + j] = (v[j] - mu) * rs * qn[c * 16 + j] * 0.08838834764831845f;
  }
  // k row dq (as dk), chunk c + k_norm
  {
    const ushort_t* src = kb + ((size_t)n * 8u + dq) * 256u + hk * 128 + c * 16;
    bf16x8 a0 = *(const bf16x8*)src, a1 = *(const bf16x8*)(src + 8);
    float v[16], s1 = 0.f, s2 = 0.f;
#pragma unroll
    for (int j = 0; j < 16; ++j) {
      v[j] = bf2f((ushort_t)(j < 8 ? a0[j] : a1[j - 8]));
      s1 += v[j]; s2 += v[j] * v[j];
    }
    for (int off = 1; off < 8; off <<= 1) { s1 += __shfl_xor(s1, off); s2 += __shfl_xor(s2, off); }
    float mu = s1 * (1.f / 128.f);
    float rs = rsqrtf(s2 * (1.f / 128.f) - mu * mu + 1e-6f);
#pragma unroll
    for (int j = 0; j < 16; ++j)
      k_s[dq * 132 + c * 16 + j] = (v[j] - mu) * rs * kn[c * 16 + j];
  }
  // v raw
  {
    const ushort_t* src = vb + ((size_t)n * 8u + dq) * 256u + hk * 128 + c * 16;
    bf16x8 a0 = *(const bf16x8*)src, a1 = *(const bf16x8*)(src + 8);
#pragma unroll
    for (int j = 0; j < 16; ++j)
      v_s[dq * 132 + c * 16 + j] = bf2f((ushort_t)(j < 8 ? a0[j] : a1[j - 8]));
  }
  __syncthreads();

  // scores: lane (dq, dk=c)
  float scv = 0.f;
#pragma unroll 16
  for (int i = 0; i < 128; ++i) scv += q_s[dq * 132 + i] * k_s[c * 132 + i];
  float mx = scv;
  for (int off = 1; off < 8; off <<= 1) mx = fmaxf(mx, __shfl_xor(mx, off));
  float e = __expf(scv - mx);
  float sum = e;
  for (int off = 1; off < 8; off <<= 1) sum += __shfl_xor(sum, off);
  a_s[dq * 9 + c] = e / sum;
  __syncthreads();

  // PV: lane (dq, chunk c)
  float o[16];
#pragma unroll
  for (int j = 0; j < 16; ++j) o[j] = 0.f;
#pragma unroll
  for (int dk = 0; dk < 8; ++dk) {
    float a = a_s[dq * 9 + dk];
#pragma unroll
    for (int j = 0; j < 16; ++j) o[j] += a * v_s[dk * 132 + c * 16 + j];
  }
  unsigned* dst = (unsigned*)(ob + ((size_t)n * 8u + dq) * 512u + w * 128 + c * 16);
#pragma unroll
  for (int j = 0; j < 8; ++j)
    dst[j] = (unsigned)f2bf(o[2 * j]) | ((unsigned)f2bf(o[2 * j + 1]) << 16);
}

// ---------------- launch ----------------
extern "C" void kernel_launch(void* const* d_in, const int* in_sizes, int n_in,
                              void* d_out, int out_size, void* d_ws, size_t ws_size,
                              hipStream_t stream) {
  const float* series = (const float*)d_in[0];
  const float* Wi = (const float*)d_in[1];
  const float* Wh = (const float*)d_in[2];
  const float* b = (const float*)d_in[3];
  const float* lns = (const float*)d_in[4];
  const float* lnb = (const float*)d_in[5];
  const float* Wq = (const float*)d_in[6];
  const float* Wk = (const float*)d_in[7];
  const float* Wv = (const float*)d_in[8];
  const float* qn = (const float*)d_in[9];
  const float* kn = (const float*)d_in[10];
  const float* Wo = (const float*)d_in[11];
  const float* Wd = (const float*)d_in[12];
  char* ws = (char*)d_ws;

  ushort_t* wit = (ushort_t*)(ws + OFF_WIT);
  ushort_t* wht = (ushort_t*)(ws + OFF_WHT);
  ushort_t* qkvt = (ushort_t*)(ws + OFF_QKVT);
  ushort_t* wot = (ushort_t*)(ws + OFF_WOT);
  ushort_t* wdt = (ushort_t*)(ws + OFF_WDT);
  float* bp = (float*)(ws + OFF_BP);
  ushort_t* hb0 = (ushort_t*)(ws + OFF_HB0);
  ushort_t* hb1 = (ushort_t*)(ws + OFF_HB1);
  float* cst = (float*)(ws + OFF_CST);
  ushort_t* sert = (ushort_t*)(ws + OFF_SERT);
  ushort_t* xzc = (ushort_t*)(ws + OFF_XZC);
  ushort_t* hidb = (ushort_t*)(ws + OFF_HID);
  ushort_t* normed = (ushort_t*)(ws + OFF_NORM);
  ushort_t* qb = (ushort_t*)(ws + OFF_QB);
  ushort_t* kb = (ushort_t*)(ws + OFF_KB);
  ushort_t* vb = (ushort_t*)(ws + OFF_VB);
  ushort_t* ob = (ushort_t*)(ws + OFF_O);
  ushort_t* mixb = (ushort_t*)(ws + OFF_MIX);

  prep_kernel<<<10760, 256, 0, stream>>>(Wi, Wh, Wq, Wk, Wv, Wo, Wd, b, ws);
  transpose_kernel<<<dim3(128, 16), 256, 0, stream>>>(series, sert);

  // LSTM: 4 chunks of 64 steps; xz chunk GEMM interleaved (stream-serial)
  for (int ch = 0; ch < 4; ++ch) {
    gemm_kernel<256, 2048, 4><<<dim3(128, 32), 256, 0, stream>>>(
        sert, wit, bp, xzc, nullptr, nullptr, nullptr, nullptr, nullptr, ch * 64);
    for (int k = 0; k < 64; ++k) {
      int t = ch * 64 + k;
      const ushort_t* hp = (t & 1) ? hb1 : hb0;
      ushort_t* hn = (t & 1) ? hb0 : hb1;
      lstm_step_kernel<<<dim3(2, 64), 256, 0, stream>>>(hp, hn, cst, wht, xzc, hidb, t);
    }
  }

  ln_kernel<<<8192, 256, 0, stream>>>(hidb, lns, lnb, normed);

  // q/k/v = normed @ [Wq|Wk|Wv] (bf16 out)
  gemm_kernel<512, 1024, 1><<<dim3(512, 16), 256, 0, stream>>>(
      normed, qkvt, nullptr, qb, kb, vb, nullptr, nullptr, nullptr, 0);

  attn_kernel<<<4096, 256, 0, stream>>>(qb, kb, vb, qn, kn, ob);

  // mix = o @ Wo -> bf16
  gemm_kernel<512, 512, 2><<<dim3(512, 8), 256, 0, stream>>>(
      ob, wot, nullptr, mixb, nullptr, nullptr, nullptr, nullptr, nullptr, 0);

  // out = (hid + mix) @ Wdown -> f32 d_out
  gemm_kernel<512, 256, 3><<<dim3(512, 4), 256, 0, stream>>>(
      nullptr, wdt, nullptr, nullptr, nullptr, nullptr, (float*)d_out, hidb, mixb, 0);
}